// Round 9
// baseline (484.049 us; speedup 1.0000x reference)
//
#include <hip/hip_runtime.h>
#include <hip/hip_bf16.h>

#define N_NODES 12000
#define N_EDGES 384000
#define PADR 12032            // 12000 rounded up to 128 (376 row-blocks of 32)
#define MAXDEG 128            // fixed slab stride; true max degree ~60 (Binom mean 32)

typedef __attribute__((ext_vector_type(8))) short bf16x8;
typedef __attribute__((ext_vector_type(16))) float f32x16;
typedef __attribute__((ext_vector_type(8))) unsigned short u16x8;

// exact 3-plane bf16 split: a = h0 + h1 + h2 (residuals exact in fp32)
__device__ __forceinline__ void split3f(float a, unsigned short& u0,
                                        unsigned short& u1, unsigned short& u2) {
    __hip_bfloat16 b0 = __float2bfloat16(a);
    float f0 = __bfloat162float(b0);
    float r1 = a - f0;
    __hip_bfloat16 b1 = __float2bfloat16(r1);
    float f1 = __bfloat162float(b1);
    float r2 = r1 - f1;
    __hip_bfloat16 b2 = __float2bfloat16(r2);
    u0 = *(unsigned short*)&b0;
    u1 = *(unsigned short*)&b1;
    u2 = *(unsigned short*)&b2;
}

// MFMA-fragment-native layout: element (row, k3) of a [rows][K3] bf16 matrix
// lives at ((R*KB + kb)*64 + h*32 + r)*8 + e, R=row>>5, r=row&31,
// kb=k3>>4, h=(k3>>3)&1, e=k3&7.  A wave's 32x16 fragment = contiguous 1KB.
__device__ __forceinline__ size_t frag_off(int row, int k3, int KB) {
    return ((size_t)((row >> 5) * KB + (k3 >> 4)) * 64
            + (((k3 >> 3) & 1) * 32) + (row & 31)) * 8 + (k3 & 7);
}

struct WArgs { const float* w[10]; unsigned short* o[10]; };

// ====== packed: slab scatter (count+scatter in one atomic) + splitX + splitW ===
// roles by blockIdx.x: [0,1500) scatter; [1500,3000) splitX; [3000,4280) splitW.
// All mutually independent.  blockIdx.z = branch.
__global__ __launch_bounds__(256) void k_scatter_splits(
    const int* ei0, const int* ei1, int* c0, int* c1, int* b0, int* b1,
    const float* x0, const float* x1, unsigned short* s0, unsigned short* s1,
    WArgs wa, int n, int ne) {
    int bx = blockIdx.x, z = blockIdx.z;
    if (bx < 1500) {
        int e = bx * 256 + threadIdx.x;
        const int* ei = z ? ei1 : ei0;
        int* cnt = z ? c1 : c0;
        int* bk = z ? b1 : b0;
        if (e < ne) {
            int d = ei[ne + e];                      // dst = ei[1][e]
            int slot = atomicAdd(&cnt[d], 1);
            if (slot < MAXDEG) bk[(d << 7) + slot] = e;
        }
    } else if (bx < 3000) {
        const float* x = z ? x1 : x0;
        unsigned short* s = z ? s1 : s0;
        int i = (bx - 1500) * 256 + threadIdx.x;
        if (i >= n * 32) return;
        int row = i >> 5, k0 = (i & 31) * 8;
        float4 f0 = *(const float4*)(x + (size_t)row * 256 + k0);
        float4 f1 = *(const float4*)(x + (size_t)row * 256 + k0 + 4);
        float vv[8] = {f0.x, f0.y, f0.z, f0.w, f1.x, f1.y, f1.z, f1.w};
        u16x8 q0, q1, q2;
#pragma unroll
        for (int e = 0; e < 8; ++e) {
            unsigned short u0, u1, u2;
            split3f(vv[e], u0, u1, u2);
            q0[e] = u0; q1[e] = u1; q2[e] = u2;
        }
        *(u16x8*)(s + frag_off(row, k0, 48))       = q0;
        *(u16x8*)(s + frag_off(row, 256 + k0, 48)) = q1;
        *(u16x8*)(s + frag_off(row, 512 + k0, 48)) = q2;
    } else {
        const int Ks[5]  = {256, 256, 256, 256, 128};
        const int Nsh[5] = {8, 8, 8, 7, 6};
        int w = bx - 3000;
        int layer = w >> 8;
        int lbx = w & 255;
        int K = Ks[layer], nsh = Nsh[layer], N = 1 << nsh;
        int KB = (3 * K) >> 4;
        const float* W = wa.w[layer * 2 + z];
        unsigned short* O = wa.o[layer * 2 + z];
        int i = lbx * 256 + threadIdx.x;
        if (i >= K * N) return;
        int k = i >> nsh, nn = i & (N - 1);
        unsigned short u0, u1, u2;
        split3f(W[i], u0, u1, u2);
        O[frag_off(nn, k, KB)]           = u0;
        O[frag_off(nn, K + k, KB)]       = u1;
        O[frag_off(nn, 2 * K + k, KB)]   = u2;
    }
}

// per-edge (src, norm) packed into one int2, slab layout (holes past cnt[d])
__global__ __launch_bounds__(256) void k_enorm_slab(
    const int* bo0, const int* bo1, const int* c0, const int* c1,
    const int* ei0, const int* ei1, const float* w0, const float* w1,
    const float* v0, const float* v1, int2* e0, int2* e1, int ne) {
    int z = blockIdx.z;
    int d = blockIdx.x * 2 + (threadIdx.x >> 7);
    int k = threadIdx.x & 127;
    const int* cnt = z ? c1 : c0;
    if (k >= cnt[d]) return;
    int idx = (d << 7) + k;
    const int* bout = z ? bo1 : bo0;
    const int* ei = z ? ei1 : ei0;
    const float* ew = z ? w1 : w0;
    const float* dv = z ? v1 : v0;
    int2* ee = z ? e1 : e0;
    int e = bout[idx];
    int s = ei[e];
    float en = (dv[s] * ew[e]) * dv[d];   // dv[d] == dv[ei[1][e]] -> bit-exact
    int2 pk; pk.x = s; pk.y = __float_as_int(en);
    ee[idx] = pk;
}

// ================= MFMA dense GEMM (6-product 3-plane bf16) =================
// MI = number of 32-row A blocks per workgroup tile (1 or 2).  MI=1 doubles the
// wave count (~3 waves/SIMD) to hide L2 load latency; per-output-chain MFMA
// order is unchanged (blocks just partition M differently) -> bit-exact.
// 1D grid with XCD-chunked mapping (y innermost -> A-panel L2-hot).

#define LOADAB(aa, bb, kb)                                                                         \
    {                                                                                              \
        _Pragma("unroll")                                                                          \
        for (int mi_ = 0; mi_ < MI; ++mi_) {                                                       \
            _Pragma("unroll")                                                                      \
            for (int p_ = 0; p_ < 3; ++p_)                                                         \
                aa[p_][mi_] = *(const bf16x8*)(A + ((size_t)((Ra + mi_) * KB + p_ * KD16 + (kb)) * 64 + lane) * 8); \
        }                                                                                          \
        _Pragma("unroll")                                                                          \
        for (int ni_ = 0; ni_ < 2; ++ni_) {                                                        \
            _Pragma("unroll")                                                                      \
            for (int q_ = 0; q_ < 3; ++q_)                                                         \
                bb[q_][ni_] = *(const bf16x8*)(B + ((size_t)((Rb + ni_) * KB + q_ * KD16 + (kb)) * 64 + lane) * 8); \
        }                                                                                          \
    }

#define DOMFMA(aa, bb)                                                                             \
    {                                                                                              \
        _Pragma("unroll")                                                                          \
        for (int mi_ = 0; mi_ < MI; ++mi_) {                                                       \
            _Pragma("unroll")                                                                      \
            for (int ni_ = 0; ni_ < 2; ++ni_) {                                                    \
                f32x16 c = acc[mi_][ni_];                                                          \
                c = __builtin_amdgcn_mfma_f32_32x32x16_bf16(aa[0][mi_], bb[0][ni_], c, 0, 0, 0);   \
                c = __builtin_amdgcn_mfma_f32_32x32x16_bf16(aa[0][mi_], bb[1][ni_], c, 0, 0, 0);   \
                c = __builtin_amdgcn_mfma_f32_32x32x16_bf16(aa[1][mi_], bb[0][ni_], c, 0, 0, 0);   \
                c = __builtin_amdgcn_mfma_f32_32x32x16_bf16(aa[1][mi_], bb[1][ni_], c, 0, 0, 0);   \
                c = __builtin_amdgcn_mfma_f32_32x32x16_bf16(aa[0][mi_], bb[2][ni_], c, 0, 0, 0);   \
                c = __builtin_amdgcn_mfma_f32_32x32x16_bf16(aa[2][mi_], bb[0][ni_], c, 0, 0, 0);   \
                acc[mi_][ni_] = c;                                                                 \
            }                                                                                      \
        }                                                                                          \
    }

template<int OUTMODE, int MI>
__device__ __forceinline__ void gemm_dense_body(
    int f, int nwg,
    const unsigned short* __restrict__ A0, const unsigned short* __restrict__ A1,
    const unsigned short* __restrict__ B0, const unsigned short* __restrict__ B1,
    const float* __restrict__ bias0, const float* __restrict__ bias1,
    float* __restrict__ C0, float* __restrict__ C1,
    unsigned short* __restrict__ P0, unsigned short* __restrict__ P1,
    int M, int K, int N) {
    int wg = (f & 7) * (nwg >> 3) + (f >> 3);   // nwg % 8 == 0
    int NY = (N + 127) >> 7;                    // 2 for N=256, else 1
    int y  = wg % NY;
    int t  = wg / NY;
    int z  = t & 1;
    int bx = t >> 1;

    const unsigned short* A = z ? A1 : A0;
    const unsigned short* B = z ? B1 : B0;
    const float* bias = z ? bias1 : bias0;
    float* C = z ? C1 : C0;
    unsigned short* P = z ? P1 : P0;

    int tid = threadIdx.x;
    int wave = tid >> 6, lane = tid & 63;
    int r = lane & 31, h = lane >> 5;
    int i0 = bx * (MI * 32);
    int j0 = y * 128 + wave * 64;
    int KB = (3 * K) >> 4;
    int KD16 = K >> 4;                      // 16 or 8, always even
    int Ra = i0 >> 5, Rb = j0 >> 5;

    f32x16 acc[MI][2] = {};

    bf16x8 aP[3][MI], bP[3][2], aQ[3][MI], bQ[3][2];
    LOADAB(aP, bP, 0);
    for (int kb0 = 0; kb0 < KD16; kb0 += 2) {
        LOADAB(aQ, bQ, kb0 + 1);            // KD16 even -> kb0+1 always valid
        DOMFMA(aP, bP);
        if (kb0 + 2 < KD16) LOADAB(aP, bP, kb0 + 2);
        DOMFMA(aQ, bQ);
    }

    int KBo = (3 * N) >> 4;
#pragma unroll
    for (int mi = 0; mi < MI; ++mi)
#pragma unroll
        for (int ni = 0; ni < 2; ++ni) {
            int gc = j0 + ni * 32 + r;
            if (OUTMODE == 1 && gc >= N) continue;
            size_t ob[3];
            if (OUTMODE == 1) {
                int Ro = (i0 + mi * 32) >> 5;
#pragma unroll
                for (int p = 0; p < 3; ++p) {
                    int k3 = p * N + gc;
                    ob[p] = ((size_t)(Ro * KBo + (k3 >> 4)) * 64
                             + (((k3 >> 3) & 1) * 32)) * 8 + (k3 & 7);
                }
            }
#pragma unroll
            for (int reg = 0; reg < 16; ++reg) {
                int rr = (reg & 3) + 8 * (reg >> 2) + 4 * h;
                int gr = i0 + mi * 32 + rr;
                if (gr >= M) continue;
                float v = acc[mi][ni][reg];
                if (OUTMODE == 0) {
                    if (gc < N) C[(size_t)gr * N + gc] = v;
                } else {
                    v = fmaxf(v + bias[gc], 0.f);
                    unsigned short u0, u1, u2;
                    split3f(v, u0, u1, u2);
                    P[ob[0] + (size_t)rr * 8] = u0;
                    P[ob[1] + (size_t)rr * 8] = u1;
                    P[ob[2] + (size_t)rr * 8] = u2;
                }
            }
        }
}

template<int OUTMODE>
__global__ __launch_bounds__(128) void gemm_mfma_dense(
    const unsigned short* __restrict__ A0, const unsigned short* __restrict__ A1,
    const unsigned short* __restrict__ B0, const unsigned short* __restrict__ B1,
    const float* __restrict__ bias0, const float* __restrict__ bias1,
    float* __restrict__ C0, float* __restrict__ C1,
    unsigned short* __restrict__ P0, unsigned short* __restrict__ P1,
    int M, int K, int N) {
    gemm_dense_body<OUTMODE, 1>(blockIdx.x, gridDim.x, A0, A1, B0, B1,
                                bias0, bias1, C0, C1, P0, P1, M, K, N);
}

// ============ packed: gemm1 (xs @ W1 -> xw, MI=1) + slab ranksort/dinv ========
// blocks [0,1504): gemm1 (tid<128; 1504%8==0 keeps the XCD chunk mapping);
// [1504,7504): wave-per-dst rank sort (by eid, deterministic) + weighted degree.
__global__ __launch_bounds__(256) void k_gemm1_ranksort(
    const unsigned short* __restrict__ xs0, const unsigned short* __restrict__ xs1,
    const unsigned short* __restrict__ w0, const unsigned short* __restrict__ w1,
    float* __restrict__ xw0, float* __restrict__ xw1,
    const int* c0, const int* c1, const int* bi0, const int* bi1,
    int* bo0, int* bo1, const float* ew0, const float* ew1,
    float* v0, float* v1) {
    int bid = blockIdx.x;
    if (bid < 1504) {
        if (threadIdx.x >= 128) return;
        gemm_dense_body<0, 1>(bid, 1504, xs0, xs1, w0, w1, nullptr, nullptr,
                              xw0, xw1, nullptr, nullptr, N_NODES, 256, 256);
        return;
    }
    int rb = bid - 1504;              // [0,6000)
    int z = rb >= 3000;
    int i = rb - z * 3000;
    const int* cnt = z ? c1 : c0;
    const int* bin = z ? bi1 : bi0;
    int* bout = z ? bo1 : bo0;
    const float* ew = z ? ew1 : ew0;
    float* dvp = z ? v1 : v0;
    int wv = threadIdx.x >> 6, lane = threadIdx.x & 63;
    int d = i * 4 + wv;
    int p0 = d << 7, dg = cnt[d];
    float tot = 0.f;
    for (int cb = 0; cb < dg; cb += 64) {
        int ii = cb + lane;
        int e = (ii < dg) ? bin[p0 + ii] : 0x7fffffff;
        int rank = 0;
        if (dg <= 64) {
            for (int j = 0; j < 64; ++j) { int vj = __shfl(e, j); rank += (int)(vj < e); }
        } else {
            for (int j = 0; j < dg; ++j) rank += (int)(bin[p0 + j] < e);
        }
        float wval = 0.f;
        if (ii < dg) { bout[p0 + rank] = e; wval = ew[e]; }
        for (int m = 1; m < 64; m <<= 1) wval += __shfl_xor(wval, m);
        tot += wval;
    }
    if (lane == 0) {
        float degf = 1.0f + tot;
        dvp[d] = (float)(1.0 / sqrt((double)degf));
    }
}

// ================= GCN aggregation (XCD-pinned column chunks, slab CSR) =======
// out = fragment-layout planes (K3=768) of relu(sum norm*xw[src] + dinv^2*xw[d] + b)
// combo = blockIdx.x & 7 -> (col_chunk, branch) pinned to one XCD; per-XCD gather
// working set 3.07 MB < 4 MB L2.
// NEW: wave = ONE dst; its 4 16-lane groups are the 4 accumulation STREAMS
// (group g takes edges j == g mod 4; final dg%4 edges -> stream 0; self-term
// initializes stream 0).  Removes intra-wave degree divergence (wave time ~ own
// dg, not max of 4 dsts).  Stream-sequential edge order and the final
// (a0+a1)+(a2+a3) combine (ordered xor16 + shfl+32) are IDENTICAL to the old
// 4-stream rule -> bit-exact.
__global__ __launch_bounds__(256) void gcn_agg(
    const float* __restrict__ xw0, const float* __restrict__ xw1,
    const int* __restrict__ c0, const int* __restrict__ c1,
    const int2* __restrict__ e0, const int2* __restrict__ e1,
    const float* __restrict__ v0, const float* __restrict__ v1,
    const float* __restrict__ b0, const float* __restrict__ b1,
    unsigned short* __restrict__ o0, unsigned short* __restrict__ o1) {
    int bid = blockIdx.x;
    int combo = bid & 7;          // -> XCD (round-robin dispatch)
    int i = bid >> 3;             // 0..2999 dst-quad within combo
    int c = combo >> 1, z = combo & 1;
    const float* xw = z ? xw1 : xw0;
    const int* cnt = z ? c1 : c0;
    const int2* ee = z ? e1 : e0;
    const float* dv = z ? v1 : v0;
    const float* bias = z ? b1 : b0;
    unsigned short* out = z ? o1 : o0;

    int tid = threadIdx.x;
    int wv = tid >> 6, lane = tid & 63;
    int g = lane >> 4;            // stream id 0..3
    int t16 = lane & 15;
    int d = i * 4 + wv;           // one dst per wave
    int col = c * 64 + t16 * 4;   // 4 consecutive cols per lane (per stream copy)

    float dvd = dv[d];
    float slw = dvd * dvd;
    float4 a = make_float4(0.f, 0.f, 0.f, 0.f);
    if (g == 0) {                 // self-term opens stream 0 (as before)
        a = *(const float4*)(xw + (size_t)d * 256 + col);
        a.x *= slw; a.y *= slw; a.z *= slw; a.w *= slw;
    }

    int dg = cnt[d];
    const long long* eq = (const long long*)(ee + ((size_t)d << 7));
    long long lv = 0;
    if (dg > 0) {
        int m0 = dg < 64 ? dg : 64;
        if (lane < m0) lv = eq[lane];          // 512B coalesced wave-load
    }
    for (int cb = 0; cb < dg; cb += 64) {
        int m = dg - cb; if (m > 64) m = 64;
        long long lnx = 0;
        int nb = cb + 64;
        if (nb < dg) {
            int mn = dg - nb; if (mn > 64) mn = 64;
            if (lane < mn) lnx = eq[nb + lane];
        }
        int T = m >> 2;                        // full 4-edge blocks
        int t = 0;
        for (; t + 4 <= T; t += 4) {           // 4 edges in flight per stream
            long long ev0 = __shfl(lv, 4 * t + g);
            long long ev1 = __shfl(lv, 4 * t + 4 + g);
            long long ev2 = __shfl(lv, 4 * t + 8 + g);
            long long ev3 = __shfl(lv, 4 * t + 12 + g);
            int s_0 = (int)ev0, s_1 = (int)ev1, s_2 = (int)ev2, s_3 = (int)ev3;
            float w_0 = __int_as_float((int)(ev0 >> 32));
            float w_1 = __int_as_float((int)(ev1 >> 32));
            float w_2 = __int_as_float((int)(ev2 >> 32));
            float w_3 = __int_as_float((int)(ev3 >> 32));
            float4 v_0 = *(const float4*)(xw + (size_t)s_0 * 256 + col);
            float4 v_1 = *(const float4*)(xw + (size_t)s_1 * 256 + col);
            float4 v_2 = *(const float4*)(xw + (size_t)s_2 * 256 + col);
            float4 v_3 = *(const float4*)(xw + (size_t)s_3 * 256 + col);
            // stream-sequential accumulation (ascending edge order per stream)
            a.x += w_0 * v_0.x; a.y += w_0 * v_0.y; a.z += w_0 * v_0.z; a.w += w_0 * v_0.w;
            a.x += w_1 * v_1.x; a.y += w_1 * v_1.y; a.z += w_1 * v_1.z; a.w += w_1 * v_1.w;
            a.x += w_2 * v_2.x; a.y += w_2 * v_2.y; a.z += w_2 * v_2.z; a.w += w_2 * v_2.w;
            a.x += w_3 * v_3.x; a.y += w_3 * v_3.y; a.z += w_3 * v_3.z; a.w += w_3 * v_3.w;
        }
        for (; t < T; ++t) {
            long long ev = __shfl(lv, 4 * t + g);
            int s = (int)ev;
            float w = __int_as_float((int)(ev >> 32));
            float4 v = *(const float4*)(xw + (size_t)s * 256 + col);
            a.x += w * v.x; a.y += w * v.y; a.z += w * v.z; a.w += w * v.w;
        }
        int rem = m & 3;                       // final partial 4-block -> stream 0
        for (int u = 0; u < rem; ++u) {
            long long ev = __shfl(lv, 4 * T + u);
            int s = (int)ev;
            float w = __int_as_float((int)(ev >> 32));
            float4 v = *(const float4*)(xw + (size_t)s * 256 + col);
            if (g == 0) { a.x += w * v.x; a.y += w * v.y; a.z += w * v.z; a.w += w * v.w; }
        }
        lv = lnx;
    }

    // combine: (a0+a1)+(a2+a3), exact old bracketing.
    // step 1: a += xor16 -> group0 holds a0+a1 (a0 first), group2 holds a2+a3.
    a.x = a.x + __shfl_xor(a.x, 16);
    a.y = a.y + __shfl_xor(a.y, 16);
    a.z = a.z + __shfl_xor(a.z, 16);
    a.w = a.w + __shfl_xor(a.w, 16);
    // step 2: group0 reads group2's (a2+a3).
    float4 acc;
    acc.x = a.x + __shfl(a.x, t16 + 32);
    acc.y = a.y + __shfl(a.y, t16 + 32);
    acc.z = a.z + __shfl(a.z, t16 + 32);
    acc.w = a.w + __shfl(a.w, t16 + 32);

    if (lane < 16) {
        float4 bb = *(const float4*)(bias + col);
        float h0 = fmaxf(acc.x + bb.x, 0.f);
        float h1 = fmaxf(acc.y + bb.y, 0.f);
        float h2 = fmaxf(acc.z + bb.z, 0.f);
        float h3 = fmaxf(acc.w + bb.w, 0.f);
        ushort4 q0, q1, q2;
        split3f(h0, q0.x, q1.x, q2.x);
        split3f(h1, q0.y, q1.y, q2.y);
        split3f(h2, q0.z, q1.z, q2.z);
        split3f(h3, q0.w, q1.w, q2.w);
        *(ushort4*)(out + frag_off(d, col, 48))       = q0;
        *(ushort4*)(out + frag_off(d, 256 + col, 48)) = q1;
        *(ushort4*)(out + frag_off(d, 512 + col, 48)) = q2;
    }
}

// ================= fused l2+l3: P2 @ W_l2 -> (LDS planes) @ W_l3 -> emb ========
// Phase 1 = exact l2 GEMM (K=256,N=128); epilogue writes split3 planes into LDS
// in fragment layout (KB=24, 48KB).  Phase 2 = l3 (K=128,N=64) reading A from
// LDS; wave w handles output cols [w*32, w*32+32).  Same MFMA order per
// accumulator, same split3 values -> bit-exact vs separate l2/l3 launches.
__global__ __launch_bounds__(128) void gemm_l2l3(
    const unsigned short* __restrict__ A0, const unsigned short* __restrict__ A1,
    const unsigned short* __restrict__ B0, const unsigned short* __restrict__ B1,
    const unsigned short* __restrict__ B20, const unsigned short* __restrict__ B21,
    const float* __restrict__ bias20, const float* __restrict__ bias21,
    const float* __restrict__ bias30, const float* __restrict__ bias31,
    unsigned short* __restrict__ E0, unsigned short* __restrict__ E1) {
    const int nwg = 376;
    const int MI = 2;
    int f = blockIdx.x;
    int wg = (f & 7) * (nwg >> 3) + (f >> 3);
    int z = wg & 1;
    int bx = wg >> 1;               // [0,188)
    const unsigned short* A = z ? A1 : A0;
    const unsigned short* B = z ? B1 : B0;
    const unsigned short* B2 = z ? B21 : B20;
    const float* bias2 = z ? bias21 : bias20;
    const float* bias3 = z ? bias31 : bias30;
    unsigned short* E = z ? E1 : E0;

    __shared__ unsigned short sP[2 * 24 * 512];   // 64 rows x K3=384, KB=24 (48KB)

    int tid = threadIdx.x;
    int wave = tid >> 6, lane = tid & 63;
    int r = lane & 31, h = lane >> 5;
    int i0 = bx * 64;
    int j0 = wave * 64;             // phase-1 cols (2 waves cover N=128)
    const int KB = 48;
    const int KD16 = 16;            // K=256
    int Ra = i0 >> 5, Rb = j0 >> 5;

    f32x16 acc[2][2] = {};
    bf16x8 aP[3][2], bP[3][2], aQ[3][2], bQ[3][2];
    LOADAB(aP, bP, 0);
    for (int kb0 = 0; kb0 < KD16; kb0 += 2) {
        LOADAB(aQ, bQ, kb0 + 1);
        DOMFMA(aP, bP);
        if (kb0 + 2 < KD16) LOADAB(aP, bP, kb0 + 2);
        DOMFMA(aQ, bQ);
    }

    // phase-1 epilogue -> LDS fragment planes (local rows 0..63)
#pragma unroll
    for (int mi = 0; mi < 2; ++mi)
#pragma unroll
        for (int ni = 0; ni < 2; ++ni) {
            int gc = j0 + ni * 32 + r;    // [0,128)
#pragma unroll
            for (int reg = 0; reg < 16; ++reg) {
                int rr = (reg & 3) + 8 * (reg >> 2) + 4 * h;
                int lr = mi * 32 + rr;
                float v = fmaxf(acc[mi][ni][reg] + bias2[gc], 0.f);
                unsigned short u0, u1, u2;
                split3f(v, u0, u1, u2);
                sP[frag_off(lr, gc, 24)]       = u0;
                sP[frag_off(lr, 128 + gc, 24)] = u1;
                sP[frag_off(lr, 256 + gc, 24)] = u2;
            }
        }
    __syncthreads();

    // phase 2: l3 (K=128, N=64); wave w -> cols [w*32, w*32+32)
    f32x16 acc2[2] = {};
    int Rb2 = wave;
#pragma unroll
    for (int kb = 0; kb < 8; ++kb) {
        bf16x8 aa[3][2], bb[3];
#pragma unroll
        for (int mi = 0; mi < 2; ++mi)
#pragma unroll
            for (int p = 0; p < 3; ++p)
                aa[p][mi] = *(const bf16x8*)&sP[((size_t)(mi * 24 + p * 8 + kb) * 64 + lane) * 8];
#pragma unroll
        for (int q = 0; q < 3; ++q)
            bb[q] = *(const bf16x8*)(B2 + ((size_t)(Rb2 * 24 + q * 8 + kb) * 64 + lane) * 8);
#pragma unroll
        for (int mi = 0; mi < 2; ++mi) {
            f32x16 c = acc2[mi];
            c = __builtin_amdgcn_mfma_f32_32x32x16_bf16(aa[0][mi], bb[0], c, 0, 0, 0);
            c = __builtin_amdgcn_mfma_f32_32x32x16_bf16(aa[0][mi], bb[1], c, 0, 0, 0);
            c = __builtin_amdgcn_mfma_f32_32x32x16_bf16(aa[1][mi], bb[0], c, 0, 0, 0);
            c = __builtin_amdgcn_mfma_f32_32x32x16_bf16(aa[1][mi], bb[1], c, 0, 0, 0);
            c = __builtin_amdgcn_mfma_f32_32x32x16_bf16(aa[0][mi], bb[2], c, 0, 0, 0);
            c = __builtin_amdgcn_mfma_f32_32x32x16_bf16(aa[2][mi], bb[0], c, 0, 0, 0);
            acc2[mi] = c;
        }
    }

    // phase-2 epilogue: emb fragments (N=64, KBo=12)
    const int KBo = 12;
    int gc = wave * 32 + r;           // [0,64)
#pragma unroll
    for (int mi = 0; mi < 2; ++mi) {
        size_t ob[3];
        int Ro = (i0 + mi * 32) >> 5;
#pragma unroll
        for (int p = 0; p < 3; ++p) {
            int k3 = p * 64 + gc;
            ob[p] = ((size_t)(Ro * KBo + (k3 >> 4)) * 64
                     + (((k3 >> 3) & 1) * 32)) * 8 + (k3 & 7);
        }
#pragma unroll
        for (int reg = 0; reg < 16; ++reg) {
            int rr = (reg & 3) + 8 * (reg >> 2) + 4 * h;
            int gr = i0 + mi * 32 + rr;
            if (gr >= N_NODES) continue;
            float v = fmaxf(acc2[mi][reg] + bias3[gc], 0.f);
            unsigned short u0, u1, u2;
            split3f(v, u0, u1, u2);
            E[ob[0] + (size_t)rr * 8] = u0;
            E[ob[1] + (size_t)rr * 8] = u1;
            E[ob[2] + (size_t)rr * 8] = u2;
        }
    }
}

// ================= final NT GEMM via bf16 MFMA (fragment layout, K3=192) ======
// C is write-once, never re-read -> nontemporal fp32 stores (full-line streams).
__global__ __launch_bounds__(256) void gemm_nt_mfma(
    const unsigned short* __restrict__ A, const unsigned short* __restrict__ B,
    float* __restrict__ C, int M, int N) {
    const int NWG = 94 * 94;
    int flat = blockIdx.y * 94 + blockIdx.x;
    int xcd = flat & 7, base = flat >> 3;
    const int q = NWG >> 3, rem = NWG & 7;
    int wg = (xcd < rem ? xcd * (q + 1) : rem * (q + 1) + (xcd - rem) * q) + base;
    int bx = wg % 94, by = wg / 94;

    int tid = threadIdx.x;
    int wave = tid >> 6, lane = tid & 63;
    int wm = wave >> 1, wn = wave & 1;
    int r = lane & 31, h = lane >> 5;
    int i0 = bx * 128 + wm * 64;
    int j0 = by * 128 + wn * 64;
    int Ra = i0 >> 5, Rb = j0 >> 5;
    const int KB = 12;

    f32x16 acc[2][2] = {};

#pragma unroll
    for (int kb0 = 0; kb0 < 4; ++kb0) {
        bf16x8 a[3][2], b[3][2];
#pragma unroll
        for (int mi = 0; mi < 2; ++mi)
#pragma unroll
            for (int p = 0; p < 3; ++p)
                a[p][mi] = *(const bf16x8*)(A + ((size_t)((Ra + mi) * KB + p * 4 + kb0) * 64 + lane) * 8);
#pragma unroll
        for (int ni = 0; ni < 2; ++ni)
#pragma unroll
            for (int p = 0; p < 3; ++p)
                b[p][ni] = *(const bf16x8*)(B + ((size_t)((Rb + ni) * KB + p * 4 + kb0) * 64 + lane) * 8);
#pragma unroll
        for (int mi = 0; mi < 2; ++mi)
#pragma unroll
            for (int ni = 0; ni < 2; ++ni) {
                f32x16 c = acc[mi][ni];
                c = __builtin_amdgcn_mfma_f32_32x32x16_bf16(a[0][mi], b[0][ni], c, 0, 0, 0);
                c = __builtin_amdgcn_mfma_f32_32x32x16_bf16(a[0][mi], b[1][ni], c, 0, 0, 0);
                c = __builtin_amdgcn_mfma_f32_32x32x16_bf16(a[1][mi], b[0][ni], c, 0, 0, 0);
                c = __builtin_amdgcn_mfma_f32_32x32x16_bf16(a[1][mi], b[1][ni], c, 0, 0, 0);
                c = __builtin_amdgcn_mfma_f32_32x32x16_bf16(a[0][mi], b[2][ni], c, 0, 0, 0);
                c = __builtin_amdgcn_mfma_f32_32x32x16_bf16(a[2][mi], b[0][ni], c, 0, 0, 0);
                acc[mi][ni] = c;
            }
    }

#pragma unroll
    for (int mi = 0; mi < 2; ++mi)
#pragma unroll
        for (int ni = 0; ni < 2; ++ni) {
            int gc = j0 + ni * 32 + r;
            if (gc >= N) continue;
#pragma unroll
            for (int reg = 0; reg < 16; ++reg) {
                int rr = (reg & 3) + 8 * (reg >> 2) + 4 * h;
                int gr = i0 + mi * 32 + rr;
                if (gr < M)
                    __builtin_nontemporal_store(acc[mi][ni][reg], &C[(size_t)gr * N + gc]);
            }
        }
}

// ================= host launch =================

static inline char* carve(char*& p, size_t bytes) {
    char* r = p;
    p += (bytes + 255) & ~(size_t)255;
    return r;
}

extern "C" void kernel_launch(void* const* d_in, const int* in_sizes, int n_in,
                              void* d_out, int out_size, void* d_ws, size_t ws_size,
                              hipStream_t stream) {
    const int n = N_NODES, ne = N_EDGES;

    const float* x[2]  = {(const float*)d_in[0], (const float*)d_in[1]};
    const float* ew[2] = {(const float*)d_in[2], (const float*)d_in[3]};
    const int*   ei[2] = {(const int*)d_in[4], (const int*)d_in[5]};
    const float* g1w[2] = {(const float*)d_in[6],  (const float*)d_in[16]};
    const float* g1b[2] = {(const float*)d_in[7],  (const float*)d_in[17]};
    const float* g2w[2] = {(const float*)d_in[8],  (const float*)d_in[18]};
    const float* g2b[2] = {(const float*)d_in[9],  (const float*)d_in[19]};
    const float* l1w[2] = {(const float*)d_in[10], (const float*)d_in[20]};
    const float* l1b[2] = {(const float*)d_in[11], (const float*)d_in[21]};
    const float* l2w[2] = {(const float*)d_in[12], (const float*)d_in[22]};
    const float* l2b[2] = {(const float*)d_in[13], (const float*)d_in[23]};
    const float* l3w[2] = {(const float*)d_in[14], (const float*)d_in[24]};
    const float* l3b[2] = {(const float*)d_in[15], (const float*)d_in[25]};

    char* p = (char*)d_ws;
    unsigned short *xs[2], *P1[2], *P2[2], *emb[2], *wt[2][5];
    float *xw[2], *dinv[2];
    int *cntB, *cnt[2], *bucket[2], *bucket2[2];
    int2* ee[2];
    const size_t RB = PADR / 32;
    const size_t wtRows[5] = {256, 256, 256, 128, 128};
    const size_t wtKB[5]   = {48, 48, 48, 48, 24};
    cntB = (int*)carve(p, (size_t)2 * n * 4);      // cnt[0] | cnt[1] adjacent -> 1 memset
    cnt[0] = cntB; cnt[1] = cntB + n;
    for (int z = 0; z < 2; ++z) {
        xs[z]   = (unsigned short*)carve(p, RB * 48 * 512 * 2);
        P1[z]   = (unsigned short*)carve(p, RB * 48 * 512 * 2);
        P2[z]   = (unsigned short*)carve(p, RB * 48 * 512 * 2);
        emb[z]  = (unsigned short*)carve(p, RB * 12 * 512 * 2);
        for (int l = 0; l < 5; ++l)
            wt[z][l] = (unsigned short*)carve(p, (wtRows[l] / 32) * wtKB[l] * 512 * 2);
        xw[z]   = (float*)carve(p, (size_t)n * 256 * 4);
        dinv[z] = (float*)carve(p, (size_t)n * 4);
        bucket[z]  = (int*)carve(p, (size_t)n * MAXDEG * 4);
        bucket2[z] = (int*)carve(p, (size_t)n * MAXDEG * 4);
        ee[z]      = (int2*)carve(p, (size_t)n * MAXDEG * 8);
    }

    dim3 blk(256);
    dim3 blkg(128);

    WArgs wa;
    const float* wsrc[2][5] = {{g1w[0], g2w[0], l1w[0], l2w[0], l3w[0]},
                               {g1w[1], g2w[1], l1w[1], l2w[1], l3w[1]}};
    for (int l = 0; l < 5; ++l)
        for (int z = 0; z < 2; ++z) { wa.w[l * 2 + z] = wsrc[z][l]; wa.o[l * 2 + z] = wt[z][l]; }

    // --- zero degree counters (single capture-safe DMA fill) ---
    hipMemsetAsync(cntB, 0, (size_t)2 * n * 4, stream);

    // --- packed: slab scatter (count+scatter fused) + splitX + splitW ---
    k_scatter_splits<<<dim3(4280, 1, 2), blk, 0, stream>>>(
        ei[0], ei[1], cnt[0], cnt[1], bucket[0], bucket[1],
        x[0], x[1], xs[0], xs[1], wa, n, ne);

    // --- packed: gemm1 (needs splits, MI=1) + ranksort/dinv (needs slab) ---
    k_gemm1_ranksort<<<dim3(7504), blk, 0, stream>>>(
        xs[0], xs[1], wt[0][0], wt[1][0], xw[0], xw[1],
        cnt[0], cnt[1], bucket[0], bucket[1], bucket2[0], bucket2[1],
        ew[0], ew[1], dinv[0], dinv[1]);

    // --- edge (src,norm) slab (needs all dinv) ---
    k_enorm_slab<<<dim3(n / 2, 1, 2), blk, 0, stream>>>(
        bucket2[0], bucket2[1], cnt[0], cnt[1], ei[0], ei[1],
        ew[0], ew[1], dinv[0], dinv[1], ee[0], ee[1], ne);

    // --- branch networks ---
    gcn_agg<<<dim3((n / 4) * 8), blk, 0, stream>>>(xw[0], xw[1], cnt[0], cnt[1],
                                                   ee[0], ee[1],
                                                   dinv[0], dinv[1], g1b[0], g1b[1],
                                                   P1[0], P1[1]);
    gemm_mfma_dense<0><<<dim3(1504), blkg, 0, stream>>>(
        P1[0], P1[1], wt[0][1], wt[1][1], nullptr, nullptr,
        xw[0], xw[1], nullptr, nullptr, n, 256, 256);
    gcn_agg<<<dim3((n / 4) * 8), blk, 0, stream>>>(xw[0], xw[1], cnt[0], cnt[1],
                                                   ee[0], ee[1],
                                                   dinv[0], dinv[1], g2b[0], g2b[1],
                                                   P1[0], P1[1]);
    gemm_mfma_dense<1><<<dim3(1504), blkg, 0, stream>>>(
        P1[0], P1[1], wt[0][2], wt[1][2], l1b[0], l1b[1],
        nullptr, nullptr, P2[0], P2[1], n, 256, 256);
    gemm_l2l3<<<dim3(376), blkg, 0, stream>>>(
        P2[0], P2[1], wt[0][3], wt[1][3], wt[0][4], wt[1][4],
        l2b[0], l2b[1], l3b[0], l3b[1], emb[0], emb[1]);

    // --- final: out = emb_dis @ emb_drug^T ---
    gemm_nt_mfma<<<dim3(94, 94, 1), blk, 0, stream>>>(emb[0], emb[1], (float*)d_out, n, n);
}

// Round 10
// 461.858 us; speedup vs baseline: 1.0480x; 1.0480x over previous
//
#include <hip/hip_runtime.h>
#include <hip/hip_bf16.h>

#define N_NODES 12000
#define N_EDGES 384000
#define PADR 12032            // 12000 rounded up to 128 (376 row-blocks of 32)
#define MAXDEG 128            // fixed slab stride; true max degree ~60 (Binom mean 32)

typedef __attribute__((ext_vector_type(8))) short bf16x8;
typedef __attribute__((ext_vector_type(16))) float f32x16;
typedef __attribute__((ext_vector_type(8))) unsigned short u16x8;

// exact 3-plane bf16 split: a = h0 + h1 + h2 (residuals exact in fp32)
__device__ __forceinline__ void split3f(float a, unsigned short& u0,
                                        unsigned short& u1, unsigned short& u2) {
    __hip_bfloat16 b0 = __float2bfloat16(a);
    float f0 = __bfloat162float(b0);
    float r1 = a - f0;
    __hip_bfloat16 b1 = __float2bfloat16(r1);
    float f1 = __bfloat162float(b1);
    float r2 = r1 - f1;
    __hip_bfloat16 b2 = __float2bfloat16(r2);
    u0 = *(unsigned short*)&b0;
    u1 = *(unsigned short*)&b1;
    u2 = *(unsigned short*)&b2;
}

// MFMA-fragment-native layout: element (row, k3) of a [rows][K3] bf16 matrix
// lives at ((R*KB + kb)*64 + h*32 + r)*8 + e, R=row>>5, r=row&31,
// kb=k3>>4, h=(k3>>3)&1, e=k3&7.  A wave's 32x16 fragment = contiguous 1KB.
__device__ __forceinline__ size_t frag_off(int row, int k3, int KB) {
    return ((size_t)((row >> 5) * KB + (k3 >> 4)) * 64
            + (((k3 >> 3) & 1) * 32) + (row & 31)) * 8 + (k3 & 7);
}

struct WArgs { const float* w[10]; unsigned short* o[10]; };

// ====== packed: slab scatter (count+scatter in one atomic) + splitX + splitW ===
// roles by blockIdx.x: [0,1500) scatter; [1500,3000) splitX; [3000,4280) splitW.
// All mutually independent.  blockIdx.z = branch.
__global__ __launch_bounds__(256) void k_scatter_splits(
    const int* ei0, const int* ei1, int* c0, int* c1, int* b0, int* b1,
    const float* x0, const float* x1, unsigned short* s0, unsigned short* s1,
    WArgs wa, int n, int ne) {
    int bx = blockIdx.x, z = blockIdx.z;
    if (bx < 1500) {
        int e = bx * 256 + threadIdx.x;
        const int* ei = z ? ei1 : ei0;
        int* cnt = z ? c1 : c0;
        int* bk = z ? b1 : b0;
        if (e < ne) {
            int d = ei[ne + e];                      // dst = ei[1][e]
            int slot = atomicAdd(&cnt[d], 1);
            if (slot < MAXDEG) bk[(d << 7) + slot] = e;
        }
    } else if (bx < 3000) {
        const float* x = z ? x1 : x0;
        unsigned short* s = z ? s1 : s0;
        int i = (bx - 1500) * 256 + threadIdx.x;
        if (i >= n * 32) return;
        int row = i >> 5, k0 = (i & 31) * 8;
        float4 f0 = *(const float4*)(x + (size_t)row * 256 + k0);
        float4 f1 = *(const float4*)(x + (size_t)row * 256 + k0 + 4);
        float vv[8] = {f0.x, f0.y, f0.z, f0.w, f1.x, f1.y, f1.z, f1.w};
        u16x8 q0, q1, q2;
#pragma unroll
        for (int e = 0; e < 8; ++e) {
            unsigned short u0, u1, u2;
            split3f(vv[e], u0, u1, u2);
            q0[e] = u0; q1[e] = u1; q2[e] = u2;
        }
        *(u16x8*)(s + frag_off(row, k0, 48))       = q0;
        *(u16x8*)(s + frag_off(row, 256 + k0, 48)) = q1;
        *(u16x8*)(s + frag_off(row, 512 + k0, 48)) = q2;
    } else {
        const int Ks[5]  = {256, 256, 256, 256, 128};
        const int Nsh[5] = {8, 8, 8, 7, 6};
        int w = bx - 3000;
        int layer = w >> 8;
        int lbx = w & 255;
        int K = Ks[layer], nsh = Nsh[layer], N = 1 << nsh;
        int KB = (3 * K) >> 4;
        const float* W = wa.w[layer * 2 + z];
        unsigned short* O = wa.o[layer * 2 + z];
        int i = lbx * 256 + threadIdx.x;
        if (i >= K * N) return;
        int k = i >> nsh, nn = i & (N - 1);
        unsigned short u0, u1, u2;
        split3f(W[i], u0, u1, u2);
        O[frag_off(nn, k, KB)]           = u0;
        O[frag_off(nn, K + k, KB)]       = u1;
        O[frag_off(nn, 2 * K + k, KB)]   = u2;
    }
}

// per-edge (src, norm) packed into one int2, slab layout (holes past cnt[d])
__global__ __launch_bounds__(256) void k_enorm_slab(
    const int* bo0, const int* bo1, const int* c0, const int* c1,
    const int* ei0, const int* ei1, const float* w0, const float* w1,
    const float* v0, const float* v1, int2* e0, int2* e1, int ne) {
    int z = blockIdx.z;
    int d = blockIdx.x * 2 + (threadIdx.x >> 7);
    int k = threadIdx.x & 127;
    const int* cnt = z ? c1 : c0;
    if (k >= cnt[d]) return;
    int idx = (d << 7) + k;
    const int* bout = z ? bo1 : bo0;
    const int* ei = z ? ei1 : ei0;
    const float* ew = z ? w1 : w0;
    const float* dv = z ? v1 : v0;
    int2* ee = z ? e1 : e0;
    int e = bout[idx];
    int s = ei[e];
    float en = (dv[s] * ew[e]) * dv[d];   // dv[d] == dv[ei[1][e]] -> bit-exact
    int2 pk; pk.x = s; pk.y = __float_as_int(en);
    ee[idx] = pk;
}

// ================= MFMA dense GEMM (6-product 3-plane bf16) =================
// MI = number of 32-row A blocks per workgroup tile (1 or 2).  MI=1 doubles the
// wave count (~3 waves/SIMD) to hide L2 load latency; per-output-chain MFMA
// order is unchanged (blocks just partition M differently) -> bit-exact.
// 1D grid with XCD-chunked mapping (y innermost -> A-panel L2-hot).

#define LOADAB(aa, bb, kb)                                                                         \
    {                                                                                              \
        _Pragma("unroll")                                                                          \
        for (int mi_ = 0; mi_ < MI; ++mi_) {                                                       \
            _Pragma("unroll")                                                                      \
            for (int p_ = 0; p_ < 3; ++p_)                                                         \
                aa[p_][mi_] = *(const bf16x8*)(A + ((size_t)((Ra + mi_) * KB + p_ * KD16 + (kb)) * 64 + lane) * 8); \
        }                                                                                          \
        _Pragma("unroll")                                                                          \
        for (int ni_ = 0; ni_ < 2; ++ni_) {                                                        \
            _Pragma("unroll")                                                                      \
            for (int q_ = 0; q_ < 3; ++q_)                                                         \
                bb[q_][ni_] = *(const bf16x8*)(B + ((size_t)((Rb + ni_) * KB + q_ * KD16 + (kb)) * 64 + lane) * 8); \
        }                                                                                          \
    }

#define DOMFMA(aa, bb)                                                                             \
    {                                                                                              \
        _Pragma("unroll")                                                                          \
        for (int mi_ = 0; mi_ < MI; ++mi_) {                                                       \
            _Pragma("unroll")                                                                      \
            for (int ni_ = 0; ni_ < 2; ++ni_) {                                                    \
                f32x16 c = acc[mi_][ni_];                                                          \
                c = __builtin_amdgcn_mfma_f32_32x32x16_bf16(aa[0][mi_], bb[0][ni_], c, 0, 0, 0);   \
                c = __builtin_amdgcn_mfma_f32_32x32x16_bf16(aa[0][mi_], bb[1][ni_], c, 0, 0, 0);   \
                c = __builtin_amdgcn_mfma_f32_32x32x16_bf16(aa[1][mi_], bb[0][ni_], c, 0, 0, 0);   \
                c = __builtin_amdgcn_mfma_f32_32x32x16_bf16(aa[1][mi_], bb[1][ni_], c, 0, 0, 0);   \
                c = __builtin_amdgcn_mfma_f32_32x32x16_bf16(aa[0][mi_], bb[2][ni_], c, 0, 0, 0);   \
                c = __builtin_amdgcn_mfma_f32_32x32x16_bf16(aa[2][mi_], bb[0][ni_], c, 0, 0, 0);   \
                acc[mi_][ni_] = c;                                                                 \
            }                                                                                      \
        }                                                                                          \
    }

template<int OUTMODE, int MI>
__device__ __forceinline__ void gemm_dense_body(
    int f, int nwg,
    const unsigned short* __restrict__ A0, const unsigned short* __restrict__ A1,
    const unsigned short* __restrict__ B0, const unsigned short* __restrict__ B1,
    const float* __restrict__ bias0, const float* __restrict__ bias1,
    float* __restrict__ C0, float* __restrict__ C1,
    unsigned short* __restrict__ P0, unsigned short* __restrict__ P1,
    int M, int K, int N) {
    int wg = (f & 7) * (nwg >> 3) + (f >> 3);   // nwg % 8 == 0
    int NY = (N + 127) >> 7;                    // 2 for N=256, else 1
    int y  = wg % NY;
    int t  = wg / NY;
    int z  = t & 1;
    int bx = t >> 1;

    const unsigned short* A = z ? A1 : A0;
    const unsigned short* B = z ? B1 : B0;
    const float* bias = z ? bias1 : bias0;
    float* C = z ? C1 : C0;
    unsigned short* P = z ? P1 : P0;

    int tid = threadIdx.x;
    int wave = tid >> 6, lane = tid & 63;
    int r = lane & 31, h = lane >> 5;
    int i0 = bx * (MI * 32);
    int j0 = y * 128 + wave * 64;
    int KB = (3 * K) >> 4;
    int KD16 = K >> 4;                      // 16 or 8, always even
    int Ra = i0 >> 5, Rb = j0 >> 5;

    f32x16 acc[MI][2] = {};

    bf16x8 aP[3][MI], bP[3][2], aQ[3][MI], bQ[3][2];
    LOADAB(aP, bP, 0);
    for (int kb0 = 0; kb0 < KD16; kb0 += 2) {
        LOADAB(aQ, bQ, kb0 + 1);            // KD16 even -> kb0+1 always valid
        DOMFMA(aP, bP);
        if (kb0 + 2 < KD16) LOADAB(aP, bP, kb0 + 2);
        DOMFMA(aQ, bQ);
    }

    int KBo = (3 * N) >> 4;
#pragma unroll
    for (int mi = 0; mi < MI; ++mi)
#pragma unroll
        for (int ni = 0; ni < 2; ++ni) {
            int gc = j0 + ni * 32 + r;
            if (OUTMODE == 1 && gc >= N) continue;
            size_t ob[3];
            if (OUTMODE == 1) {
                int Ro = (i0 + mi * 32) >> 5;
#pragma unroll
                for (int p = 0; p < 3; ++p) {
                    int k3 = p * N + gc;
                    ob[p] = ((size_t)(Ro * KBo + (k3 >> 4)) * 64
                             + (((k3 >> 3) & 1) * 32)) * 8 + (k3 & 7);
                }
            }
#pragma unroll
            for (int reg = 0; reg < 16; ++reg) {
                int rr = (reg & 3) + 8 * (reg >> 2) + 4 * h;
                int gr = i0 + mi * 32 + rr;
                if (gr >= M) continue;
                float v = acc[mi][ni][reg];
                if (OUTMODE == 0) {
                    if (gc < N) C[(size_t)gr * N + gc] = v;
                } else {
                    v = fmaxf(v + bias[gc], 0.f);
                    unsigned short u0, u1, u2;
                    split3f(v, u0, u1, u2);
                    P[ob[0] + (size_t)rr * 8] = u0;
                    P[ob[1] + (size_t)rr * 8] = u1;
                    P[ob[2] + (size_t)rr * 8] = u2;
                }
            }
        }
}

template<int OUTMODE>
__global__ __launch_bounds__(128) void gemm_mfma_dense(
    const unsigned short* __restrict__ A0, const unsigned short* __restrict__ A1,
    const unsigned short* __restrict__ B0, const unsigned short* __restrict__ B1,
    const float* __restrict__ bias0, const float* __restrict__ bias1,
    float* __restrict__ C0, float* __restrict__ C1,
    unsigned short* __restrict__ P0, unsigned short* __restrict__ P1,
    int M, int K, int N) {
    gemm_dense_body<OUTMODE, 1>(blockIdx.x, gridDim.x, A0, A1, B0, B1,
                                bias0, bias1, C0, C1, P0, P1, M, K, N);
}

// ============ packed: gemm1 (xs @ W1 -> xw, MI=1) + slab ranksort/dinv ========
// blocks [0,1504): gemm1 (tid<128; 1504%8==0 keeps the XCD chunk mapping);
// [1504,7504): wave-per-dst rank sort (by eid, deterministic) + weighted degree.
__global__ __launch_bounds__(256) void k_gemm1_ranksort(
    const unsigned short* __restrict__ xs0, const unsigned short* __restrict__ xs1,
    const unsigned short* __restrict__ w0, const unsigned short* __restrict__ w1,
    float* __restrict__ xw0, float* __restrict__ xw1,
    const int* c0, const int* c1, const int* bi0, const int* bi1,
    int* bo0, int* bo1, const float* ew0, const float* ew1,
    float* v0, float* v1) {
    int bid = blockIdx.x;
    if (bid < 1504) {
        if (threadIdx.x >= 128) return;
        gemm_dense_body<0, 1>(bid, 1504, xs0, xs1, w0, w1, nullptr, nullptr,
                              xw0, xw1, nullptr, nullptr, N_NODES, 256, 256);
        return;
    }
    int rb = bid - 1504;              // [0,6000)
    int z = rb >= 3000;
    int i = rb - z * 3000;
    const int* cnt = z ? c1 : c0;
    const int* bin = z ? bi1 : bi0;
    int* bout = z ? bo1 : bo0;
    const float* ew = z ? ew1 : ew0;
    float* dvp = z ? v1 : v0;
    int wv = threadIdx.x >> 6, lane = threadIdx.x & 63;
    int d = i * 4 + wv;
    int p0 = d << 7, dg = cnt[d];
    float tot = 0.f;
    for (int cb = 0; cb < dg; cb += 64) {
        int ii = cb + lane;
        int e = (ii < dg) ? bin[p0 + ii] : 0x7fffffff;
        int rank = 0;
        if (dg <= 64) {
            for (int j = 0; j < 64; ++j) { int vj = __shfl(e, j); rank += (int)(vj < e); }
        } else {
            for (int j = 0; j < dg; ++j) rank += (int)(bin[p0 + j] < e);
        }
        float wval = 0.f;
        if (ii < dg) { bout[p0 + rank] = e; wval = ew[e]; }
        for (int m = 1; m < 64; m <<= 1) wval += __shfl_xor(wval, m);
        tot += wval;
    }
    if (lane == 0) {
        float degf = 1.0f + tot;
        dvp[d] = (float)(1.0 / sqrt((double)degf));
    }
}

// ================= GCN aggregation (XCD-pinned column chunks, slab CSR) =======
// out = fragment-layout planes (K3=768) of relu(sum norm*xw[src] + dinv^2*xw[d] + b)
// combo = blockIdx.x & 7 -> (col_chunk, branch) pinned to one XCD; per-XCD gather
// working set 3.07 MB < 4 MB L2.  Edge (src,norm) = one 8B slab load, chunk loads
// double-buffered.  fp32 accumulate order bit-exact vs original 4-stream version.
__global__ __launch_bounds__(256) void gcn_agg(
    const float* __restrict__ xw0, const float* __restrict__ xw1,
    const int* __restrict__ c0, const int* __restrict__ c1,
    const int2* __restrict__ e0, const int2* __restrict__ e1,
    const float* __restrict__ v0, const float* __restrict__ v1,
    const float* __restrict__ b0, const float* __restrict__ b1,
    unsigned short* __restrict__ o0, unsigned short* __restrict__ o1) {
    int bid = blockIdx.x;
    int combo = bid & 7;          // -> XCD (round-robin dispatch)
    int i = bid >> 3;             // 0..749 dst-block within combo
    int c = combo >> 1, z = combo & 1;
    const float* xw = z ? xw1 : xw0;
    const int* cnt = z ? c1 : c0;
    const int2* ee = z ? e1 : e0;
    const float* dv = z ? v1 : v0;
    const float* bias = z ? b1 : b0;
    unsigned short* out = z ? o1 : o0;

    int tid = threadIdx.x;
    int lane = tid & 63;
    int t16 = lane & 15;
    int base = lane & 48;         // first lane of this 16-lane group
    int d = i * 16 + (tid >> 4);  // dst node for this group
    int col = c * 64 + t16 * 4;   // 4 consecutive cols per lane

    float dvd = dv[d];
    float slw = dvd * dvd;
    float4 a0 = *(const float4*)(xw + (size_t)d * 256 + col);
    a0.x *= slw; a0.y *= slw; a0.z *= slw; a0.w *= slw;
    float4 a1 = make_float4(0.f, 0.f, 0.f, 0.f);
    float4 a2 = make_float4(0.f, 0.f, 0.f, 0.f);
    float4 a3 = make_float4(0.f, 0.f, 0.f, 0.f);

    int dg = cnt[d];
    const long long* eq = (const long long*)(ee + ((size_t)d << 7));
    long long vcur = 0;
    if (dg > 0) {
        int m0 = dg < 16 ? dg : 16;
        if (t16 < m0) vcur = eq[t16];
    }
    for (int cb = 0; cb < dg; cb += 16) {
        int m = dg - cb; if (m > 16) m = 16;
        long long vnx = 0;
        int nb = cb + 16;
        if (nb < dg) {
            int mn = dg - nb; if (mn > 16) mn = 16;
            if (t16 < mn) vnx = eq[nb + t16];
        }
        int sl_ = (int)vcur;
        float wl_ = __int_as_float((int)(vcur >> 32));
        int j = 0;
        for (; j + 4 <= m; j += 4) {
            int s_0 = __shfl(sl_, base + j),     s_1 = __shfl(sl_, base + j + 1);
            int s_2 = __shfl(sl_, base + j + 2), s_3 = __shfl(sl_, base + j + 3);
            float w_0 = __shfl(wl_, base + j),     w_1 = __shfl(wl_, base + j + 1);
            float w_2 = __shfl(wl_, base + j + 2), w_3 = __shfl(wl_, base + j + 3);
            float4 v_0 = *(const float4*)(xw + (size_t)s_0 * 256 + col);
            float4 v_1 = *(const float4*)(xw + (size_t)s_1 * 256 + col);
            float4 v_2 = *(const float4*)(xw + (size_t)s_2 * 256 + col);
            float4 v_3 = *(const float4*)(xw + (size_t)s_3 * 256 + col);
            a0.x += w_0 * v_0.x; a0.y += w_0 * v_0.y; a0.z += w_0 * v_0.z; a0.w += w_0 * v_0.w;
            a1.x += w_1 * v_1.x; a1.y += w_1 * v_1.y; a1.z += w_1 * v_1.z; a1.w += w_1 * v_1.w;
            a2.x += w_2 * v_2.x; a2.y += w_2 * v_2.y; a2.z += w_2 * v_2.z; a2.w += w_2 * v_2.w;
            a3.x += w_3 * v_3.x; a3.y += w_3 * v_3.y; a3.z += w_3 * v_3.z; a3.w += w_3 * v_3.w;
        }
        for (; j < m; ++j) {                 // tail of final partial 4-block -> a0
            int s = __shfl(sl_, base + j);
            float wn = __shfl(wl_, base + j);
            float4 v = *(const float4*)(xw + (size_t)s * 256 + col);
            a0.x += wn * v.x; a0.y += wn * v.y; a0.z += wn * v.z; a0.w += wn * v.w;
        }
        vcur = vnx;
    }
    float4 acc;
    acc.x = (a0.x + a1.x) + (a2.x + a3.x);
    acc.y = (a0.y + a1.y) + (a2.y + a3.y);
    acc.z = (a0.z + a1.z) + (a2.z + a3.z);
    acc.w = (a0.w + a1.w) + (a2.w + a3.w);

    float4 bb = *(const float4*)(bias + col);
    float h0 = fmaxf(acc.x + bb.x, 0.f);
    float h1 = fmaxf(acc.y + bb.y, 0.f);
    float h2 = fmaxf(acc.z + bb.z, 0.f);
    float h3 = fmaxf(acc.w + bb.w, 0.f);
    ushort4 q0, q1, q2;
    split3f(h0, q0.x, q1.x, q2.x);
    split3f(h1, q0.y, q1.y, q2.y);
    split3f(h2, q0.z, q1.z, q2.z);
    split3f(h3, q0.w, q1.w, q2.w);
    *(ushort4*)(out + frag_off(d, col, 48))       = q0;
    *(ushort4*)(out + frag_off(d, 256 + col, 48)) = q1;
    *(ushort4*)(out + frag_off(d, 512 + col, 48)) = q2;
}

// ================= fused l2+l3: P2 @ W_l2 -> (LDS planes) @ W_l3 -> emb ========
// Phase 1 = exact l2 GEMM (K=256,N=128); epilogue writes split3 planes into LDS
// in fragment layout (KB=24, 48KB).  Phase 2 = l3 (K=128,N=64) reading A from
// LDS; wave w handles output cols [w*32, w*32+32).  Same MFMA order per
// accumulator, same split3 values -> bit-exact vs separate l2/l3 launches.
__global__ __launch_bounds__(128) void gemm_l2l3(
    const unsigned short* __restrict__ A0, const unsigned short* __restrict__ A1,
    const unsigned short* __restrict__ B0, const unsigned short* __restrict__ B1,
    const unsigned short* __restrict__ B20, const unsigned short* __restrict__ B21,
    const float* __restrict__ bias20, const float* __restrict__ bias21,
    const float* __restrict__ bias30, const float* __restrict__ bias31,
    unsigned short* __restrict__ E0, unsigned short* __restrict__ E1) {
    const int nwg = 376;
    const int MI = 2;
    int f = blockIdx.x;
    int wg = (f & 7) * (nwg >> 3) + (f >> 3);
    int z = wg & 1;
    int bx = wg >> 1;               // [0,188)
    const unsigned short* A = z ? A1 : A0;
    const unsigned short* B = z ? B1 : B0;
    const unsigned short* B2 = z ? B21 : B20;
    const float* bias2 = z ? bias21 : bias20;
    const float* bias3 = z ? bias31 : bias30;
    unsigned short* E = z ? E1 : E0;

    __shared__ unsigned short sP[2 * 24 * 512];   // 64 rows x K3=384, KB=24 (48KB)

    int tid = threadIdx.x;
    int wave = tid >> 6, lane = tid & 63;
    int r = lane & 31, h = lane >> 5;
    int i0 = bx * 64;
    int j0 = wave * 64;             // phase-1 cols (2 waves cover N=128)
    const int KB = 48;
    const int KD16 = 16;            // K=256
    int Ra = i0 >> 5, Rb = j0 >> 5;

    f32x16 acc[2][2] = {};
    bf16x8 aP[3][2], bP[3][2], aQ[3][2], bQ[3][2];
    LOADAB(aP, bP, 0);
    for (int kb0 = 0; kb0 < KD16; kb0 += 2) {
        LOADAB(aQ, bQ, kb0 + 1);
        DOMFMA(aP, bP);
        if (kb0 + 2 < KD16) LOADAB(aP, bP, kb0 + 2);
        DOMFMA(aQ, bQ);
    }

    // phase-1 epilogue -> LDS fragment planes (local rows 0..63)
#pragma unroll
    for (int mi = 0; mi < 2; ++mi)
#pragma unroll
        for (int ni = 0; ni < 2; ++ni) {
            int gc = j0 + ni * 32 + r;    // [0,128)
#pragma unroll
            for (int reg = 0; reg < 16; ++reg) {
                int rr = (reg & 3) + 8 * (reg >> 2) + 4 * h;
                int lr = mi * 32 + rr;
                float v = fmaxf(acc[mi][ni][reg] + bias2[gc], 0.f);
                unsigned short u0, u1, u2;
                split3f(v, u0, u1, u2);
                sP[frag_off(lr, gc, 24)]       = u0;
                sP[frag_off(lr, 128 + gc, 24)] = u1;
                sP[frag_off(lr, 256 + gc, 24)] = u2;
            }
        }
    __syncthreads();

    // phase 2: l3 (K=128, N=64); wave w -> cols [w*32, w*32+32)
    f32x16 acc2[2] = {};
    int Rb2 = wave;
#pragma unroll
    for (int kb = 0; kb < 8; ++kb) {
        bf16x8 aa[3][2], bb[3];
#pragma unroll
        for (int mi = 0; mi < 2; ++mi)
#pragma unroll
            for (int p = 0; p < 3; ++p)
                aa[p][mi] = *(const bf16x8*)&sP[((size_t)(mi * 24 + p * 8 + kb) * 64 + lane) * 8];
#pragma unroll
        for (int q = 0; q < 3; ++q)
            bb[q] = *(const bf16x8*)(B2 + ((size_t)(Rb2 * 24 + q * 8 + kb) * 64 + lane) * 8);
#pragma unroll
        for (int mi = 0; mi < 2; ++mi) {
            f32x16 c = acc2[mi];
            c = __builtin_amdgcn_mfma_f32_32x32x16_bf16(aa[0][mi], bb[0], c, 0, 0, 0);
            c = __builtin_amdgcn_mfma_f32_32x32x16_bf16(aa[0][mi], bb[1], c, 0, 0, 0);
            c = __builtin_amdgcn_mfma_f32_32x32x16_bf16(aa[1][mi], bb[0], c, 0, 0, 0);
            c = __builtin_amdgcn_mfma_f32_32x32x16_bf16(aa[1][mi], bb[1], c, 0, 0, 0);
            c = __builtin_amdgcn_mfma_f32_32x32x16_bf16(aa[0][mi], bb[2], c, 0, 0, 0);
            c = __builtin_amdgcn_mfma_f32_32x32x16_bf16(aa[2][mi], bb[0], c, 0, 0, 0);
            acc2[mi] = c;
        }
    }

    // phase-2 epilogue: emb fragments (N=64, KBo=12)
    const int KBo = 12;
    int gc = wave * 32 + r;           // [0,64)
#pragma unroll
    for (int mi = 0; mi < 2; ++mi) {
        size_t ob[3];
        int Ro = (i0 + mi * 32) >> 5;
#pragma unroll
        for (int p = 0; p < 3; ++p) {
            int k3 = p * 64 + gc;
            ob[p] = ((size_t)(Ro * KBo + (k3 >> 4)) * 64
                     + (((k3 >> 3) & 1) * 32)) * 8 + (k3 & 7);
        }
#pragma unroll
        for (int reg = 0; reg < 16; ++reg) {
            int rr = (reg & 3) + 8 * (reg >> 2) + 4 * h;
            int gr = i0 + mi * 32 + rr;
            if (gr >= N_NODES) continue;
            float v = fmaxf(acc2[mi][reg] + bias3[gc], 0.f);
            unsigned short u0, u1, u2;
            split3f(v, u0, u1, u2);
            E[ob[0] + (size_t)rr * 8] = u0;
            E[ob[1] + (size_t)rr * 8] = u1;
            E[ob[2] + (size_t)rr * 8] = u2;
        }
    }
}

// ================= final NT GEMM via bf16 MFMA (fragment layout, K3=192) ======
// C is write-once, never re-read -> nontemporal fp32 stores (full-line streams).
__global__ __launch_bounds__(256) void gemm_nt_mfma(
    const unsigned short* __restrict__ A, const unsigned short* __restrict__ B,
    float* __restrict__ C, int M, int N) {
    const int NWG = 94 * 94;
    int flat = blockIdx.y * 94 + blockIdx.x;
    int xcd = flat & 7, base = flat >> 3;
    const int q = NWG >> 3, rem = NWG & 7;
    int wg = (xcd < rem ? xcd * (q + 1) : rem * (q + 1) + (xcd - rem) * q) + base;
    int bx = wg % 94, by = wg / 94;

    int tid = threadIdx.x;
    int wave = tid >> 6, lane = tid & 63;
    int wm = wave >> 1, wn = wave & 1;
    int r = lane & 31, h = lane >> 5;
    int i0 = bx * 128 + wm * 64;
    int j0 = by * 128 + wn * 64;
    int Ra = i0 >> 5, Rb = j0 >> 5;
    const int KB = 12;

    f32x16 acc[2][2] = {};

#pragma unroll
    for (int kb0 = 0; kb0 < 4; ++kb0) {
        bf16x8 a[3][2], b[3][2];
#pragma unroll
        for (int mi = 0; mi < 2; ++mi)
#pragma unroll
            for (int p = 0; p < 3; ++p)
                a[p][mi] = *(const bf16x8*)(A + ((size_t)((Ra + mi) * KB + p * 4 + kb0) * 64 + lane) * 8);
#pragma unroll
        for (int ni = 0; ni < 2; ++ni)
#pragma unroll
            for (int p = 0; p < 3; ++p)
                b[p][ni] = *(const bf16x8*)(B + ((size_t)((Rb + ni) * KB + p * 4 + kb0) * 64 + lane) * 8);
#pragma unroll
        for (int mi = 0; mi < 2; ++mi)
#pragma unroll
            for (int ni = 0; ni < 2; ++ni) {
                f32x16 c = acc[mi][ni];
                c = __builtin_amdgcn_mfma_f32_32x32x16_bf16(a[0][mi], b[0][ni], c, 0, 0, 0);
                c = __builtin_amdgcn_mfma_f32_32x32x16_bf16(a[0][mi], b[1][ni], c, 0, 0, 0);
                c = __builtin_amdgcn_mfma_f32_32x32x16_bf16(a[1][mi], b[0][ni], c, 0, 0, 0);
                c = __builtin_amdgcn_mfma_f32_32x32x16_bf16(a[1][mi], b[1][ni], c, 0, 0, 0);
                c = __builtin_amdgcn_mfma_f32_32x32x16_bf16(a[0][mi], b[2][ni], c, 0, 0, 0);
                c = __builtin_amdgcn_mfma_f32_32x32x16_bf16(a[2][mi], b[0][ni], c, 0, 0, 0);
                acc[mi][ni] = c;
            }
    }

#pragma unroll
    for (int mi = 0; mi < 2; ++mi)
#pragma unroll
        for (int ni = 0; ni < 2; ++ni) {
            int gc = j0 + ni * 32 + r;
            if (gc >= N) continue;
#pragma unroll
            for (int reg = 0; reg < 16; ++reg) {
                int rr = (reg & 3) + 8 * (reg >> 2) + 4 * h;
                int gr = i0 + mi * 32 + rr;
                if (gr < M)
                    __builtin_nontemporal_store(acc[mi][ni][reg], &C[(size_t)gr * N + gc]);
            }
        }
}

// ================= host launch =================

static inline char* carve(char*& p, size_t bytes) {
    char* r = p;
    p += (bytes + 255) & ~(size_t)255;
    return r;
}

extern "C" void kernel_launch(void* const* d_in, const int* in_sizes, int n_in,
                              void* d_out, int out_size, void* d_ws, size_t ws_size,
                              hipStream_t stream) {
    const int n = N_NODES, ne = N_EDGES;

    const float* x[2]  = {(const float*)d_in[0], (const float*)d_in[1]};
    const float* ew[2] = {(const float*)d_in[2], (const float*)d_in[3]};
    const int*   ei[2] = {(const int*)d_in[4], (const int*)d_in[5]};
    const float* g1w[2] = {(const float*)d_in[6],  (const float*)d_in[16]};
    const float* g1b[2] = {(const float*)d_in[7],  (const float*)d_in[17]};
    const float* g2w[2] = {(const float*)d_in[8],  (const float*)d_in[18]};
    const float* g2b[2] = {(const float*)d_in[9],  (const float*)d_in[19]};
    const float* l1w[2] = {(const float*)d_in[10], (const float*)d_in[20]};
    const float* l1b[2] = {(const float*)d_in[11], (const float*)d_in[21]};
    const float* l2w[2] = {(const float*)d_in[12], (const float*)d_in[22]};
    const float* l2b[2] = {(const float*)d_in[13], (const float*)d_in[23]};
    const float* l3w[2] = {(const float*)d_in[14], (const float*)d_in[24]};
    const float* l3b[2] = {(const float*)d_in[15], (const float*)d_in[25]};

    char* p = (char*)d_ws;
    unsigned short *xs[2], *P1[2], *P2[2], *emb[2], *wt[2][5];
    float *xw[2], *dinv[2];
    int *cntB, *cnt[2], *bucket[2], *bucket2[2];
    int2* ee[2];
    const size_t RB = PADR / 32;
    const size_t wtRows[5] = {256, 256, 256, 128, 128};
    const size_t wtKB[5]   = {48, 48, 48, 48, 24};
    cntB = (int*)carve(p, (size_t)2 * n * 4);      // cnt[0] | cnt[1] adjacent -> 1 memset
    cnt[0] = cntB; cnt[1] = cntB + n;
    for (int z = 0; z < 2; ++z) {
        xs[z]   = (unsigned short*)carve(p, RB * 48 * 512 * 2);
        P1[z]   = (unsigned short*)carve(p, RB * 48 * 512 * 2);
        P2[z]   = (unsigned short*)carve(p, RB * 48 * 512 * 2);
        emb[z]  = (unsigned short*)carve(p, RB * 12 * 512 * 2);
        for (int l = 0; l < 5; ++l)
            wt[z][l] = (unsigned short*)carve(p, (wtRows[l] / 32) * wtKB[l] * 512 * 2);
        xw[z]   = (float*)carve(p, (size_t)n * 256 * 4);
        dinv[z] = (float*)carve(p, (size_t)n * 4);
        bucket[z]  = (int*)carve(p, (size_t)n * MAXDEG * 4);
        bucket2[z] = (int*)carve(p, (size_t)n * MAXDEG * 4);
        ee[z]      = (int2*)carve(p, (size_t)n * MAXDEG * 8);
    }

    dim3 blk(256);
    dim3 blkg(128);

    WArgs wa;
    const float* wsrc[2][5] = {{g1w[0], g2w[0], l1w[0], l2w[0], l3w[0]},
                               {g1w[1], g2w[1], l1w[1], l2w[1], l3w[1]}};
    for (int l = 0; l < 5; ++l)
        for (int z = 0; z < 2; ++z) { wa.w[l * 2 + z] = wsrc[z][l]; wa.o[l * 2 + z] = wt[z][l]; }

    // --- zero degree counters (single capture-safe DMA fill) ---
    hipMemsetAsync(cntB, 0, (size_t)2 * n * 4, stream);

    // --- packed: slab scatter (count+scatter fused) + splitX + splitW ---
    k_scatter_splits<<<dim3(4280, 1, 2), blk, 0, stream>>>(
        ei[0], ei[1], cnt[0], cnt[1], bucket[0], bucket[1],
        x[0], x[1], xs[0], xs[1], wa, n, ne);

    // --- packed: gemm1 (needs splits, MI=1) + ranksort/dinv (needs slab) ---
    k_gemm1_ranksort<<<dim3(7504), blk, 0, stream>>>(
        xs[0], xs[1], wt[0][0], wt[1][0], xw[0], xw[1],
        cnt[0], cnt[1], bucket[0], bucket[1], bucket2[0], bucket2[1],
        ew[0], ew[1], dinv[0], dinv[1]);

    // --- edge (src,norm) slab (needs all dinv) ---
    k_enorm_slab<<<dim3(n / 2, 1, 2), blk, 0, stream>>>(
        bucket2[0], bucket2[1], cnt[0], cnt[1], ei[0], ei[1],
        ew[0], ew[1], dinv[0], dinv[1], ee[0], ee[1], ne);

    // --- branch networks ---
    gcn_agg<<<dim3((n / 16) * 8), blk, 0, stream>>>(xw[0], xw[1], cnt[0], cnt[1],
                                                    ee[0], ee[1],
                                                    dinv[0], dinv[1], g1b[0], g1b[1],
                                                    P1[0], P1[1]);
    gemm_mfma_dense<0><<<dim3(1504), blkg, 0, stream>>>(
        P1[0], P1[1], wt[0][1], wt[1][1], nullptr, nullptr,
        xw[0], xw[1], nullptr, nullptr, n, 256, 256);
    gcn_agg<<<dim3((n / 16) * 8), blk, 0, stream>>>(xw[0], xw[1], cnt[0], cnt[1],
                                                    ee[0], ee[1],
                                                    dinv[0], dinv[1], g2b[0], g2b[1],
                                                    P1[0], P1[1]);
    gemm_mfma_dense<1><<<dim3(1504), blkg, 0, stream>>>(
        P1[0], P1[1], wt[0][2], wt[1][2], l1b[0], l1b[1],
        nullptr, nullptr, P2[0], P2[1], n, 256, 256);
    gemm_l2l3<<<dim3(376), blkg, 0, stream>>>(
        P2[0], P2[1], wt[0][3], wt[1][3], wt[0][4], wt[1][4],
        l2b[0], l2b[1], l3b[0], l3b[1], emb[0], emb[1]);

    // --- final: out = emb_dis @ emb_drug^T ---
    gemm_nt_mfma<<<dim3(94, 94, 1), blk, 0, stream>>>(emb[0], emb[1], (float*)d_out, n, n);
}